// Round 1
// baseline (72.423 us; speedup 1.0000x reference)
//
#include <hip/hip_runtime.h>

// Reference returns x unchanged (attention path is dead code). The entire
// problem is an 8 MiB device-to-device copy: d_in[0] -> d_out.
//
// Previous version used hipMemcpyAsync, which inside graph capture runs as a
// blit/SDMA-class copy at ~234 GB/s effective (71.7 us). A plain float4 copy
// kernel runs on the CUs at ~6 TB/s: ~3 us of memory time.
//
// out_size = 8*64*4096 = 2,097,152 floats = 524,288 float4.
// 2048 blocks x 256 threads = exactly one float4 per thread (8 blocks/CU).

__global__ __launch_bounds__(256) void copy_f4(const float4* __restrict__ in,
                                               float4* __restrict__ out,
                                               int n4) {
    int i = blockIdx.x * blockDim.x + threadIdx.x;
    if (i < n4) {
        out[i] = in[i];
    }
}

extern "C" void kernel_launch(void* const* d_in, const int* in_sizes, int n_in,
                              void* d_out, int out_size, void* d_ws, size_t ws_size,
                              hipStream_t stream) {
    const float4* x = (const float4*)d_in[0];
    float4* out = (float4*)d_out;
    const int n4 = out_size / 4;  // 524,288
    const int threads = 256;
    const int blocks = (n4 + threads - 1) / threads;  // 2048
    hipLaunchKernelGGL(copy_f4, dim3(blocks), dim3(threads), 0, stream,
                       x, out, n4);
}